// Round 1
// baseline (1160.980 us; speedup 1.0000x reference)
//
#include <hip/hip_runtime.h>

// FlashAttentionVarlen, fp32, packed layout.
// B=128 seqs, LMAX=256, H=16 heads, D=64, T=24576 packed tokens.
// Masked softmax with -1e9 underflows to exactly 0 in fp32, so computing
// over valid keys only (packed, via cu_seqlens) is numerically identical
// to the padded reference. gather_idx / mask / inv_idx are unused.
//
// Design: 1 block = (seq b, head h, q-chunk of 128 rows); 1 thread = 1 q row.
// q row + output accumulator live in registers (no LDS, no barriers, no
// cross-lane reductions). K/V rows are read with wave-uniform addresses
// (compiler scalarizes / coalesces to one fetch). Online softmax with
// deferred rescale (threshold 8) keeps the inner loop at 2 FMA per element.

#define NTHREADS 128

__global__ __launch_bounds__(NTHREADS, 2)
void fa_varlen_kernel(const float* __restrict__ qg,
                      const float* __restrict__ kg,
                      const float* __restrict__ vg,
                      const int* __restrict__ cu,
                      float* __restrict__ outg) {
  constexpr int H = 16, D = 64;
  const int bid = (int)blockIdx.x;
  const int b     = bid >> 5;          // 32 blocks per sequence (16 h * 2 chunks)
  const int h     = (bid >> 1) & (H - 1);
  const int chunk = bid & 1;

  const int t0 = cu[b];
  const int L  = cu[b + 1] - t0;
  const int qrow = chunk * NTHREADS + (int)threadIdx.x;
  if (qrow >= L) return;              // only L=128 seqs' chunk 1 exits

  const size_t rowStride = (size_t)H * D;  // 1024 floats per packed token

  // ---- load q row into registers (64 VGPRs) ----
  const float* qptr = qg + (size_t)(t0 + qrow) * rowStride + (size_t)h * D;
  float qreg[D];
#pragma unroll
  for (int d = 0; d < D; d += 4) {
    const float4 t = *reinterpret_cast<const float4*>(qptr + d);
    qreg[d + 0] = t.x; qreg[d + 1] = t.y;
    qreg[d + 2] = t.z; qreg[d + 3] = t.w;
  }

  float o[D];
#pragma unroll
  for (int d = 0; d < D; ++d) o[d] = 0.0f;
  float m = -1e30f;   // running (deferred) max
  float l = 0.0f;     // running denominator

  const float* kbase = kg + (size_t)t0 * rowStride + (size_t)h * D;
  const float* vbase = vg + (size_t)t0 * rowStride + (size_t)h * D;

  for (int j = 0; j < L; ++j) {
    const float* kj = kbase + (size_t)j * rowStride;  // wave-uniform address
    const float* vj = vbase + (size_t)j * rowStride;  // wave-uniform address

    // ---- s = (q . k_j) * scale, 4 independent FMA chains ----
    float s0 = 0.f, s1 = 0.f, s2 = 0.f, s3 = 0.f;
#pragma unroll
    for (int d = 0; d < D; d += 16) {
      const float4 a  = *reinterpret_cast<const float4*>(kj + d + 0);
      const float4 b4 = *reinterpret_cast<const float4*>(kj + d + 4);
      const float4 c4 = *reinterpret_cast<const float4*>(kj + d + 8);
      const float4 e4 = *reinterpret_cast<const float4*>(kj + d + 12);
      s0 = fmaf(qreg[d +  0], a.x,  s0); s0 = fmaf(qreg[d +  1], a.y,  s0);
      s1 = fmaf(qreg[d +  2], a.z,  s1); s1 = fmaf(qreg[d +  3], a.w,  s1);
      s2 = fmaf(qreg[d +  4], b4.x, s2); s2 = fmaf(qreg[d +  5], b4.y, s2);
      s3 = fmaf(qreg[d +  6], b4.z, s3); s3 = fmaf(qreg[d +  7], b4.w, s3);
      s0 = fmaf(qreg[d +  8], c4.x, s0); s0 = fmaf(qreg[d +  9], c4.y, s0);
      s1 = fmaf(qreg[d + 10], c4.z, s1); s1 = fmaf(qreg[d + 11], c4.w, s1);
      s2 = fmaf(qreg[d + 12], e4.x, s2); s2 = fmaf(qreg[d + 13], e4.y, s2);
      s3 = fmaf(qreg[d + 14], e4.z, s3); s3 = fmaf(qreg[d + 15], e4.w, s3);
    }
    const float s = ((s0 + s1) + (s2 + s3)) * 0.125f;  // 1/sqrt(64)

    // ---- online softmax with deferred rescale (THR = 8) ----
    float p;
    if (s > m + 8.0f) {
      const float corr = __expf(m - s);   // m=-1e30 on first trigger -> corr=0
      l *= corr;
#pragma unroll
      for (int d = 0; d < D; ++d) o[d] *= corr;
      m = s;
      p = 1.0f;
    } else {
      p = __expf(s - m);                  // bounded by e^8, fp32-safe
    }
    l += p;

    // ---- o += p * v_j : 1 FMA per element (the steady-state cost) ----
#pragma unroll
    for (int d = 0; d < D; d += 4) {
      const float4 vvv = *reinterpret_cast<const float4*>(vj + d);
      o[d + 0] = fmaf(p, vvv.x, o[d + 0]);
      o[d + 1] = fmaf(p, vvv.y, o[d + 1]);
      o[d + 2] = fmaf(p, vvv.z, o[d + 2]);
      o[d + 3] = fmaf(p, vvv.w, o[d + 3]);
    }
  }

  // ---- epilogue: normalize and store ----
  const float inv_l = 1.0f / l;
  float* optr = outg + (size_t)(t0 + qrow) * rowStride + (size_t)h * D;
#pragma unroll
  for (int d = 0; d < D; d += 4) {
    float4 t;
    t.x = o[d + 0] * inv_l; t.y = o[d + 1] * inv_l;
    t.z = o[d + 2] * inv_l; t.w = o[d + 3] * inv_l;
    *reinterpret_cast<float4*>(optr + d) = t;
  }
}

extern "C" void kernel_launch(void* const* d_in, const int* in_sizes, int n_in,
                              void* d_out, int out_size, void* d_ws, size_t ws_size,
                              hipStream_t stream) {
  (void)in_sizes; (void)n_in; (void)d_ws; (void)ws_size; (void)out_size;
  const float* q  = (const float*)d_in[0];
  const float* k  = (const float*)d_in[1];
  const float* v  = (const float*)d_in[2];
  const int*   cu = (const int*)d_in[3];   // cu_seqlens_q (== cu_seqlens_k)
  float* out = (float*)d_out;

  // B * H * (LMAX/128) = 128 * 16 * 2 = 4096 blocks of 128 threads.
  fa_varlen_kernel<<<dim3(4096), dim3(NTHREADS), 0, stream>>>(q, k, v, cu, out);
}

// Round 2
// 166.769 us; speedup vs baseline: 6.9616x; 6.9616x over previous
//
#include <hip/hip_runtime.h>

// FlashAttentionVarlen via bf16 MFMA with hi/lo split (near-fp32 accuracy).
// B=128 seqs (L in {128,256}), H=16, D=64, packed T=24576, fp32 in/out.
//
// Block = (seq b, head h, 128-row q chunk): 512 threads = 8 waves x 16 q rows.
// Per 32-key tile: stage K,V to LDS as pre-split bf16 hi/lo planes (V stored
// transposed [d][key]), XOR-swizzled at 16B-slot granularity. Swapped QK^T
// (mfma(A=K, B=Q)) puts softmax stats lane-local per q row. Each logical
// matmul uses 3 MFMAs (hi*hi + lo*hi + hi*lo) so bf16 quantization error
// cancels to ~2^-17 — output accuracy matches the fp32 baseline.

using bf16x8 = __attribute__((ext_vector_type(8))) short;
using f32x4  = __attribute__((ext_vector_type(4))) float;

__device__ inline unsigned short f2bf(float x) {          // RNE f32 -> bf16
  unsigned u = __builtin_bit_cast(unsigned, x);
  return (unsigned short)((u + 0x7FFFu + ((u >> 16) & 1u)) >> 16);
}
__device__ inline float bf2f(unsigned short h) {
  unsigned u = ((unsigned)h) << 16;
  return __builtin_bit_cast(float, u);
}

#define MFMA(a, b, c) __builtin_amdgcn_mfma_f32_16x16x32_bf16((a), (b), (c), 0, 0, 0)

constexpr int H  = 16;
constexpr int D  = 64;
constexpr int RS = H * D;   // packed row stride in floats (1024)

__global__ __launch_bounds__(512, 2)
void fa_mfma_kernel(const float* __restrict__ qg, const float* __restrict__ kg,
                    const float* __restrict__ vg, const int* __restrict__ cu,
                    float* __restrict__ outg) {
  // K planes: [key 0..31][d 0..63], row = 128B = 8 x 16B slots, slot ^= (key&7)
  __shared__ unsigned short kp_hi[32 * 64], kp_lo[32 * 64];
  // V planes transposed: [d 0..63][key 0..31], row = 64B = 4 slots, slot ^= (d>>1)&3
  __shared__ unsigned short vt_hi[64 * 32], vt_lo[64 * 32];

  const int bid   = (int)blockIdx.x;
  const int b     = bid >> 5;
  const int h     = (bid >> 1) & (H - 1);
  const int chunk = bid & 1;

  const int t0 = cu[b];
  const int L  = cu[b + 1] - t0;
  if (chunk * 128 >= L) return;        // block-uniform early exit (no barriers yet)

  const int tid  = (int)threadIdx.x;
  const int lane = tid & 63;
  const int w    = tid >> 6;           // wave 0..7
  const int g    = lane >> 4;          // lane group 0..3
  const int qj   = lane & 15;          // q index within wave tile / d-sub / key-sub
  const int qbase = chunk * 128 + w * 16;

  // ---- Q fragments (B operand): lane holds Q[qj][ks*32 + g*8 + j], prescaled by 1/8 ----
  bf16x8 q_hi[2], q_lo[2];
  {
    const float* qrow = qg + (size_t)(t0 + qbase + qj) * RS + h * D;
#pragma unroll
    for (int ks = 0; ks < 2; ++ks) {
      const float4 f0 = *reinterpret_cast<const float4*>(qrow + ks * 32 + g * 8);
      const float4 f1 = *reinterpret_cast<const float4*>(qrow + ks * 32 + g * 8 + 4);
      float f[8] = {f0.x, f0.y, f0.z, f0.w, f1.x, f1.y, f1.z, f1.w};
#pragma unroll
      for (int j = 0; j < 8; ++j) {
        const float x = f[j] * 0.125f;                 // fold 1/sqrt(64)
        const unsigned short hi = f2bf(x);
        q_hi[ks][j] = (short)hi;
        q_lo[ks][j] = (short)f2bf(x - bf2f(hi));
      }
    }
  }

  f32x4 acc[4];
#pragma unroll
  for (int n = 0; n < 4; ++n) acc[n] = (f32x4){0.f, 0.f, 0.f, 0.f};
  float m    = -1e30f;
  float lsum = 0.0f;

  const float* kbase = kg + (size_t)t0 * RS + h * D;
  const float* vbase = vg + (size_t)t0 * RS + h * D;
  const int nt = L / 32;               // L in {128,256} -> 4 or 8 tiles

  for (int t = 0; t < nt; ++t) {
    __syncthreads();                   // previous tile's reads done before overwrite

    // ---- stage K tile: 32 keys x 64 d, f32 -> split bf16 planes ----
    {
      const int key   = tid >> 4;             // 0..31
      const int dbase = (tid & 15) * 4;       // 0..60
      const float4 f4 = *reinterpret_cast<const float4*>(
          kbase + (size_t)(t * 32 + key) * RS + dbase);
      const float f[4] = {f4.x, f4.y, f4.z, f4.w};
      unsigned hi01, hi23, lo01, lo23;
      {
        const unsigned short h0 = f2bf(f[0]), h1 = f2bf(f[1]),
                             h2 = f2bf(f[2]), h3 = f2bf(f[3]);
        hi01 = (unsigned)h0 | ((unsigned)h1 << 16);
        hi23 = (unsigned)h2 | ((unsigned)h3 << 16);
        const unsigned short l0 = f2bf(f[0] - bf2f(h0)), l1 = f2bf(f[1] - bf2f(h1)),
                             l2 = f2bf(f[2] - bf2f(h2)), l3 = f2bf(f[3] - bf2f(h3));
        lo01 = (unsigned)l0 | ((unsigned)l1 << 16);
        lo23 = (unsigned)l2 | ((unsigned)l3 << 16);
      }
      const int slot = dbase >> 3;
      const int idx  = key * 64 + (((slot ^ (key & 7)) << 3) | (dbase & 7));
      *reinterpret_cast<uint2*>(&kp_hi[idx]) = make_uint2(hi01, hi23);
      *reinterpret_cast<uint2*>(&kp_lo[idx]) = make_uint2(lo01, lo23);
    }

    // ---- stage V tile transposed: vt[d][key], 2 passes of 16 keys ----
#pragma unroll
    for (int pss = 0; pss < 2; ++pss) {
      const int d  = tid & 63;
      const int k0 = pss * 16 + (tid >> 6) * 2;     // even
      const float v0 = vbase[(size_t)(t * 32 + k0) * RS + d];
      const float v1 = vbase[(size_t)(t * 32 + k0 + 1) * RS + d];
      const unsigned short h0 = f2bf(v0), h1 = f2bf(v1);
      const unsigned short l0 = f2bf(v0 - bf2f(h0)), l1 = f2bf(v1 - bf2f(h1));
      const int idx = d * 32 + ((((k0 >> 3) ^ ((d >> 1) & 3)) << 3) | (k0 & 7));
      *reinterpret_cast<unsigned*>(&vt_hi[idx]) = (unsigned)h0 | ((unsigned)h1 << 16);
      *reinterpret_cast<unsigned*>(&vt_lo[idx]) = (unsigned)l0 | ((unsigned)l1 << 16);
    }
    __syncthreads();

    // ---- QK^T (swapped): s[ts] holds D[key=g*4+r (+16*ts)][q=qj] ----
    f32x4 s[2];
    s[0] = (f32x4){0.f, 0.f, 0.f, 0.f};
    s[1] = (f32x4){0.f, 0.f, 0.f, 0.f};
#pragma unroll
    for (int ts = 0; ts < 2; ++ts) {
      const int key = ts * 16 + qj;              // A-operand row
#pragma unroll
      for (int ks = 0; ks < 2; ++ks) {
        const int slot = ks * 4 + g;
        const int idx  = key * 64 + ((slot ^ (key & 7)) << 3);
        const bf16x8 khi = *reinterpret_cast<const bf16x8*>(&kp_hi[idx]);
        const bf16x8 klo = *reinterpret_cast<const bf16x8*>(&kp_lo[idx]);
        s[ts] = MFMA(khi, q_hi[ks], s[ts]);
        s[ts] = MFMA(klo, q_hi[ks], s[ts]);
        s[ts] = MFMA(khi, q_lo[ks], s[ts]);
      }
    }

    // ---- online softmax: lane owns q=qj; keys g*4+r and 16+g*4+r ----
    float tmax = fmaxf(fmaxf(fmaxf(s[0][0], s[0][1]), fmaxf(s[0][2], s[0][3])),
                       fmaxf(fmaxf(s[1][0], s[1][1]), fmaxf(s[1][2], s[1][3])));
    tmax = fmaxf(tmax, __shfl_xor(tmax, 16));
    tmax = fmaxf(tmax, __shfl_xor(tmax, 32));
    const float newm = fmaxf(m, tmax);
    float p0[4], p1[4], psum = 0.f;
#pragma unroll
    for (int r = 0; r < 4; ++r) { p0[r] = __expf(s[0][r] - newm); psum += p0[r]; }
#pragma unroll
    for (int r = 0; r < 4; ++r) { p1[r] = __expf(s[1][r] - newm); psum += p1[r]; }
    psum += __shfl_xor(psum, 16);
    psum += __shfl_xor(psum, 32);
    const float corr = __expf(m - newm);         // exactly 1.0 when unchanged
    m    = newm;
    lsum = lsum * corr + psum;
    if (!__all(corr == 1.0f)) {                  // rescale O for this wave's q rows
      const float c0 = __shfl(corr, g * 4 + 0);
      const float c1 = __shfl(corr, g * 4 + 1);
      const float c2 = __shfl(corr, g * 4 + 2);
      const float c3 = __shfl(corr, g * 4 + 3);
#pragma unroll
      for (int n = 0; n < 4; ++n) {
        acc[n][0] *= c0; acc[n][1] *= c1; acc[n][2] *= c2; acc[n][3] *= c3;
      }
    }

    // ---- redistribute P: C-layout (q=qj, key=ts*16+g*4+r) -> A-layout (q=qj, key=g*8+j)
    bf16x8 pa_hi, pa_lo;
    const int sel = g >> 1;                      // source score tile
#pragma unroll
    for (int j = 0; j < 8; ++j) {
      const int sl = (((g & 1) * 2 + (j >> 2)) << 4) + qj;   // src lane
      const float a0 = __shfl(p0[j & 3], sl);
      const float a1 = __shfl(p1[j & 3], sl);
      const float pv = sel ? a1 : a0;
      const unsigned short ph = f2bf(pv);
      pa_hi[j] = (short)ph;
      pa_lo[j] = (short)f2bf(pv - bf2f(ph));
    }

    // ---- PV: acc[n] += P * V, B-operand from transposed V planes ----
#pragma unroll
    for (int n = 0; n < 4; ++n) {
      const int d   = n * 16 + qj;
      const int idx = d * 32 + ((g ^ ((d >> 1) & 3)) << 3);
      const bf16x8 vhi = *reinterpret_cast<const bf16x8*>(&vt_hi[idx]);
      const bf16x8 vlo = *reinterpret_cast<const bf16x8*>(&vt_lo[idx]);
      acc[n] = MFMA(pa_hi, vhi, acc[n]);
      acc[n] = MFMA(pa_lo, vhi, acc[n]);
      acc[n] = MFMA(pa_hi, vlo, acc[n]);
    }
  }

  // ---- epilogue: normalize by row sum, store fp32 ----
  const float linv = 1.0f / lsum;                // valid for q=qj
#pragma unroll
  for (int r = 0; r < 4; ++r) {
    const float lr  = __shfl(linv, g * 4 + r);
    const int qrow  = qbase + g * 4 + r;
    float* op = outg + (size_t)(t0 + qrow) * RS + h * D + qj;
    op[0]  = acc[0][r] * lr;
    op[16] = acc[1][r] * lr;
    op[32] = acc[2][r] * lr;
    op[48] = acc[3][r] * lr;
  }
}

extern "C" void kernel_launch(void* const* d_in, const int* in_sizes, int n_in,
                              void* d_out, int out_size, void* d_ws, size_t ws_size,
                              hipStream_t stream) {
  (void)in_sizes; (void)n_in; (void)d_ws; (void)ws_size; (void)out_size;
  const float* q  = (const float*)d_in[0];
  const float* k  = (const float*)d_in[1];
  const float* v  = (const float*)d_in[2];
  const int*   cu = (const int*)d_in[3];
  float* out = (float*)d_out;

  // B * H * (LMAX/128) = 128*16*2 = 4096 blocks; L=128 chunk-1 blocks exit early.
  fa_mfma_kernel<<<dim3(4096), dim3(512), 0, stream>>>(q, k, v, cu, out);
}

// Round 3
// 138.661 us; speedup vs baseline: 8.3728x; 1.2027x over previous
//
#include <hip/hip_runtime.h>
#include <hip/hip_bf16.h>

// FlashAttentionVarlen, bf16-MFMA flash attention, fp32 in/out.
// B=128 seqs (L in {128,256}), H=16, D=64, packed T=24576.
// Block = (seq, head, 128-q-row chunk), 512 thr = 8 waves x 16 q rows.
// 64-key tiles; K staged to LDS as split bf16 hi/lo (QK^T error ~2^-17),
// V staged as bf16 hi only; P split hi/lo. Reg-staged double buffering:
// next tile's global loads are in flight during current tile's compute.
// Raw s_barrier + explicit lgkmcnt keeps those loads un-drained.

using bf16x8 = __attribute__((ext_vector_type(8))) short;
using u16x8  = __attribute__((ext_vector_type(8))) unsigned short;
using f32x4  = __attribute__((ext_vector_type(4))) float;

#define MFMA(a, b, c) __builtin_amdgcn_mfma_f32_16x16x32_bf16((a), (b), (c), 0, 0, 0)

constexpr int H  = 16;
constexpr int D  = 64;
constexpr int RS = H * D;   // packed token row stride in floats

__device__ inline unsigned short bfbits(float x) {
  return __builtin_bit_cast(unsigned short, __float2bfloat16(x));
}
__device__ inline float bff(unsigned short u) {
  return __bfloat162float(__builtin_bit_cast(__hip_bfloat16, u));
}

__global__ __launch_bounds__(512, 4)
void fa_mfma2_kernel(const float* __restrict__ qg, const float* __restrict__ kg,
                     const float* __restrict__ vg, const int* __restrict__ cu,
                     float* __restrict__ outg) {
  // K planes: [key 0..63][d 0..63] shorts, 8x16B slots/row, slot ^= (key&7)
  __shared__ unsigned short kp_hi[64 * 64], kp_lo[64 * 64];
  // V transposed: [d 0..63][key 0..63] shorts, slot ^= (d&7)
  __shared__ unsigned short vt_hi[64 * 64];

  const int bid   = (int)blockIdx.x;
  const int b     = bid >> 5;
  const int h     = (bid >> 1) & (H - 1);
  const int chunk = bid & 1;

  const int t0 = cu[b];
  const int L  = cu[b + 1] - t0;
  if (chunk * 128 >= L) return;        // block-uniform

  const int tid  = (int)threadIdx.x;
  const int lane = tid & 63;
  const int w    = tid >> 6;
  const int g    = lane >> 4;
  const int qj   = lane & 15;

  // staging assignments
  const int s_key = tid >> 3, s_d0 = (tid & 7) * 8;
  const int kidx  = s_key * 64 + ((((s_d0 >> 3) ^ (s_key & 7)) << 3));
  const int s_vd  = tid & 63, s_k0 = (tid >> 6) * 8;
  const int vidx  = s_vd * 64 + ((((s_k0 >> 3) ^ (s_vd & 7)) << 3));

  const float* kbase = kg + (size_t)t0 * RS + h * D;
  const float* vbase = vg + (size_t)t0 * RS + h * D;

  // ---- Q fragments (B operand), split hi/lo, prescaled by 1/8 ----
  bf16x8 qh[2], ql[2];
  {
    const float* qrow = qg + (size_t)(t0 + chunk * 128 + w * 16 + qj) * RS + h * D;
#pragma unroll
    for (int ks = 0; ks < 2; ++ks) {
      const float4 f0 = *reinterpret_cast<const float4*>(qrow + ks * 32 + g * 8);
      const float4 f1 = *reinterpret_cast<const float4*>(qrow + ks * 32 + g * 8 + 4);
      const float f[8] = {f0.x, f0.y, f0.z, f0.w, f1.x, f1.y, f1.z, f1.w};
#pragma unroll
      for (int j = 0; j < 8; ++j) {
        const float x = f[j] * 0.125f;
        const unsigned short hs = bfbits(x);
        qh[ks][j] = (short)hs;
        ql[ks][j] = (short)bfbits(x - bff(hs));
      }
    }
  }

  f32x4 acc[4];
#pragma unroll
  for (int n = 0; n < 4; ++n) acc[n] = (f32x4){0.f, 0.f, 0.f, 0.f};
  float m = -1e30f, lsum = 0.f;

  auto stage_load = [&](float4& k0r, float4& k1r, float (&vr)[8], int t) {
    const float* kr = kbase + (size_t)(t * 64 + s_key) * RS + s_d0;
    k0r = *reinterpret_cast<const float4*>(kr);
    k1r = *reinterpret_cast<const float4*>(kr + 4);
    const float* vp = vbase + (size_t)(t * 64 + s_k0) * RS + s_vd;
#pragma unroll
    for (int i = 0; i < 8; ++i) vr[i] = vp[(size_t)i * RS];
  };

  auto stage_store = [&](const float4& k0r, const float4& k1r, const float (&vr)[8]) {
    u16x8 khi, klo, vh;
    const float kf[8] = {k0r.x, k0r.y, k0r.z, k0r.w, k1r.x, k1r.y, k1r.z, k1r.w};
#pragma unroll
    for (int i = 0; i < 8; ++i) {
      const unsigned short hs = bfbits(kf[i]);
      khi[i] = hs;
      klo[i] = bfbits(kf[i] - bff(hs));
    }
#pragma unroll
    for (int i = 0; i < 8; ++i) vh[i] = bfbits(vr[i]);
    __builtin_amdgcn_s_barrier();                    // prev tile's readers done
    asm volatile("" ::: "memory");
    *reinterpret_cast<u16x8*>(kp_hi + kidx) = khi;
    *reinterpret_cast<u16x8*>(kp_lo + kidx) = klo;
    *reinterpret_cast<u16x8*>(vt_hi + vidx) = vh;
    asm volatile("s_waitcnt lgkmcnt(0)" ::: "memory");
    __builtin_amdgcn_s_barrier();                    // tile visible
    asm volatile("" ::: "memory");
  };

  auto compute_tile = [&]() {
    // ---- QK^T over 4 key-subtiles ----
    f32x4 sc[4];
#pragma unroll
    for (int kt = 0; kt < 4; ++kt) sc[kt] = (f32x4){0.f, 0.f, 0.f, 0.f};
    __builtin_amdgcn_s_setprio(1);
#pragma unroll
    for (int kt = 0; kt < 4; ++kt) {
#pragma unroll
      for (int ks = 0; ks < 2; ++ks) {
        const int idx = (kt * 16 + qj) * 64 + ((((ks * 4 + g) ^ (qj & 7)) << 3));
        const bf16x8 khi = *reinterpret_cast<const bf16x8*>(kp_hi + idx);
        const bf16x8 klo = *reinterpret_cast<const bf16x8*>(kp_lo + idx);
        sc[kt] = MFMA(khi, qh[ks], sc[kt]);
        sc[kt] = MFMA(klo, qh[ks], sc[kt]);
        sc[kt] = MFMA(khi, ql[ks], sc[kt]);
      }
    }
    __builtin_amdgcn_s_setprio(0);

    // ---- online softmax (lane owns q=qj) with deferred max ----
    float tmax = sc[0][0];
#pragma unroll
    for (int kt = 0; kt < 4; ++kt)
#pragma unroll
      for (int r = 0; r < 4; ++r) tmax = fmaxf(tmax, sc[kt][r]);
    tmax = fmaxf(tmax, __shfl_xor(tmax, 16));
    tmax = fmaxf(tmax, __shfl_xor(tmax, 32));
    if (!__all(tmax <= m + 8.0f)) {        // rare after first tile
      const float newm = fmaxf(m, tmax);
      const float corr = __expf(m - newm); // first tile: exp(-inf)=0
      m = newm;
      lsum *= corr;
#pragma unroll
      for (int r = 0; r < 4; ++r) {
        const float cr = __shfl(corr, g * 4 + r);
#pragma unroll
        for (int n = 0; n < 4; ++n) acc[n][r] *= cr;
      }
    }
    float p[4][4], psum = 0.f;
#pragma unroll
    for (int kt = 0; kt < 4; ++kt)
#pragma unroll
      for (int r = 0; r < 4; ++r) {
        p[kt][r] = __expf(sc[kt][r] - m);   // bounded by e^8
        psum += p[kt][r];
      }
    psum += __shfl_xor(psum, 16);
    psum += __shfl_xor(psum, 32);
    lsum += psum;

    // ---- PV per 32-key chunk: redistribute P (C->A layout), then MFMA ----
#pragma unroll
    for (int c = 0; c < 2; ++c) {
      bf16x8 pah, pal;
#pragma unroll
      for (int j = 0; j < 8; ++j) {
        const int sl  = (((2 * g + (j >> 2)) & 3) << 4) + qj;
        const float fa = __shfl(p[2 * c][j & 3], sl);
        const float fb = __shfl(p[2 * c + 1][j & 3], sl);
        const float pv = (g & 2) ? fb : fa;
        const unsigned short hb = bfbits(pv);
        pah[j] = (short)hb;
        pal[j] = (short)bfbits(pv - bff(hb));
      }
      __builtin_amdgcn_s_setprio(1);
#pragma unroll
      for (int n = 0; n < 4; ++n) {
        const int idx = (n * 16 + qj) * 64 + ((((4 * c + g) ^ (qj & 7)) << 3));
        const bf16x8 vh = *reinterpret_cast<const bf16x8*>(vt_hi + idx);
        acc[n] = MFMA(pah, vh, acc[n]);
        acc[n] = MFMA(pal, vh, acc[n]);
      }
      __builtin_amdgcn_s_setprio(0);
    }
  };

  // ---- main loop: reg-staged double buffer over 64-key tiles ----
  const int nt = L >> 6;                  // 2 or 4
  float4 ka0, ka1, kb0, kb1;
  float  va[8], vb[8];
  stage_load(ka0, ka1, va, 0);
  for (int t = 0; t < nt; t += 2) {
    if (t + 1 < nt) stage_load(kb0, kb1, vb, t + 1);
    stage_store(ka0, ka1, va);
    compute_tile();
    if (t + 2 < nt) stage_load(ka0, ka1, va, t + 2);
    if (t + 1 < nt) {
      stage_store(kb0, kb1, vb);
      compute_tile();
    }
  }

  // ---- epilogue ----
  const float linv = 1.0f / lsum;
#pragma unroll
  for (int r = 0; r < 4; ++r) {
    const float lr = __shfl(linv, g * 4 + r);
    const int qrow = chunk * 128 + w * 16 + g * 4 + r;
    float* op = outg + (size_t)(t0 + qrow) * RS + h * D + qj;
    op[0]  = acc[0][r] * lr;
    op[16] = acc[1][r] * lr;
    op[32] = acc[2][r] * lr;
    op[48] = acc[3][r] * lr;
  }
}

extern "C" void kernel_launch(void* const* d_in, const int* in_sizes, int n_in,
                              void* d_out, int out_size, void* d_ws, size_t ws_size,
                              hipStream_t stream) {
  (void)in_sizes; (void)n_in; (void)d_ws; (void)ws_size; (void)out_size;
  const float* q  = (const float*)d_in[0];
  const float* k  = (const float*)d_in[1];
  const float* v  = (const float*)d_in[2];
  const int*   cu = (const int*)d_in[3];
  float* out = (float*)d_out;

  fa_mfma2_kernel<<<dim3(4096), dim3(512), 0, stream>>>(q, k, v, cu, out);
}